// Round 1
// baseline (391.902 us; speedup 1.0000x reference)
//
#include <hip/hip_runtime.h>

#define NN 100000

// ---------------- zero the degree buffer ----------------
__global__ void zero_deg(float* __restrict__ deg, int n) {
    int i = blockIdx.x * blockDim.x + threadIdx.x;
    int stride = gridDim.x * blockDim.x;
    for (; i < n; i += stride) deg[i] = 0.0f;
}

// ---------------- scatter-add degrees: deg[col[e]] += w[e] ----------------
__global__ void degree_kernel(const int* __restrict__ col,
                              const float* __restrict__ w,
                              float* __restrict__ deg,
                              int e4, int e_total) {
    int i = blockIdx.x * blockDim.x + threadIdx.x;
    int stride = gridDim.x * blockDim.x;
    for (int v = i; v < e4; v += stride) {
        int4 c   = reinterpret_cast<const int4*>(col)[v];
        float4 wv = reinterpret_cast<const float4*>(w)[v];
        atomicAdd(&deg[c.x], wv.x);
        atomicAdd(&deg[c.y], wv.y);
        atomicAdd(&deg[c.z], wv.z);
        atomicAdd(&deg[c.w], wv.w);
    }
    // scalar tail (E % 4)
    for (int t = e4 * 4 + i; t < e_total; t += stride) {
        atomicAdd(&deg[col[t]], w[t]);
    }
}

// ---------------- dinv = deg==0 ? 0 : rsqrt(deg), in place ----------------
__global__ void rsqrt_kernel(float* __restrict__ deg, int n) {
    int i = blockIdx.x * blockDim.x + threadIdx.x;
    int stride = gridDim.x * blockDim.x;
    for (; i < n; i += stride) {
        float d = deg[i];
        deg[i] = (d == 0.0f) ? 0.0f : rsqrtf(d);
    }
}

// ---------------- out[e] = dinv[row[e]] * dinv[col[e]] ----------------
__global__ void norm_kernel(const int* __restrict__ row,
                            const int* __restrict__ col,
                            const float* __restrict__ dinv,
                            float* __restrict__ out,
                            int e4, int e_total) {
    int i = blockIdx.x * blockDim.x + threadIdx.x;
    int stride = gridDim.x * blockDim.x;
    for (int v = i; v < e4; v += stride) {
        int4 r = reinterpret_cast<const int4*>(row)[v];
        int4 c = reinterpret_cast<const int4*>(col)[v];
        float4 o;
        o.x = dinv[r.x] * dinv[c.x];
        o.y = dinv[r.y] * dinv[c.y];
        o.z = dinv[r.z] * dinv[c.z];
        o.w = dinv[r.w] * dinv[c.w];
        reinterpret_cast<float4*>(out)[v] = o;
    }
    // scalar tail
    for (int t = e4 * 4 + i; t < e_total; t += stride) {
        out[t] = dinv[row[t]] * dinv[col[t]];
    }
}

extern "C" void kernel_launch(void* const* d_in, const int* in_sizes, int n_in,
                              void* d_out, int out_size, void* d_ws, size_t ws_size,
                              hipStream_t stream) {
    // Inputs per reference: edge_index (2, E) int32 flat, edge_weight (E,) f32
    const int*   edge_index = (const int*)d_in[0];
    const float* edge_w     = (const float*)d_in[1];
    const int E = in_sizes[1];          // edge count
    const int* row = edge_index;        // edge_index[0]
    const int* col = edge_index + E;    // edge_index[1]

    float* deg = (float*)d_ws;          // N_NODES floats = 400 KB scratch
    float* out = (float*)d_out;

    const int B = 256;
    const int e4 = E / 4;

    // zero degree table (harness does not re-poison between replays)
    {
        int grid = min((NN + B - 1) / B, 2048);
        zero_deg<<<grid, B, 0, stream>>>(deg, NN);
    }
    // scatter-add degrees
    {
        int grid = min((e4 + B - 1) / B, 2048);
        degree_kernel<<<grid, B, 0, stream>>>(col, edge_w, deg, e4, E);
    }
    // deg -> deg^-1/2 (0-safe)
    {
        int grid = min((NN + B - 1) / B, 2048);
        rsqrt_kernel<<<grid, B, 0, stream>>>(deg, NN);
    }
    // gather-gather-multiply
    {
        int grid = min((e4 + B - 1) / B, 2048);
        norm_kernel<<<grid, B, 0, stream>>>(row, col, deg, out, e4, E);
    }
}

// Round 2
// 132.003 us; speedup vs baseline: 2.9689x; 2.9689x over previous
//
#include <hip/hip_runtime.h>

#define NN    100000
#define PART  25000      // nodes per partition; LDS = 100 KB/block
#define NPASS 4          // NPASS * PART == NN exactly

// ============ main path: privatized LDS histogram, no global atomics ========

// Each block: one (pass p, edge-chunk g). Histogram its chunk's cols that fall
// in partition p into LDS, then stream the 100 KB partial to a private slice.
__global__ __launch_bounds__(1024) void histo_kernel(
    const int* __restrict__ col, const float* __restrict__ w,
    float* __restrict__ partial,   // [NPASS*G][PART]
    int G, int e4, int e_total, int fancy_map)
{
    __shared__ float lds[PART];

    int b = blockIdx.x;
    int p, g;
    if (fancy_map) {
        // Put the NPASS blocks of one chunk on the SAME XCD (b%8 heuristic),
        // dispatched within a 32-block window -> co-resident -> L2 reuse of
        // the chunk's col/w data across passes. Requires G % 8 == 0.
        int q = b >> 5;          // group of 32 blocks
        int r = b & 31;
        int x = r & 7;           // xcd slot
        p = r >> 3;              // 0..3
        g = q * 8 + x;
    } else {
        p = b % NPASS;
        g = b / NPASS;
    }
    const int lo = p * PART;
    const int hi = lo + PART;

    for (int i = threadIdx.x; i < PART; i += blockDim.x) lds[i] = 0.0f;
    __syncthreads();

    const int C  = (e4 + G - 1) / G;
    const int v0 = g * C;
    const int v1 = min(e4, v0 + C);
    for (int v = v0 + threadIdx.x; v < v1; v += blockDim.x) {
        int4   c  = reinterpret_cast<const int4*>(col)[v];
        float4 wv = reinterpret_cast<const float4*>(w)[v];
        if (c.x >= lo && c.x < hi) atomicAdd(&lds[c.x - lo], wv.x);
        if (c.y >= lo && c.y < hi) atomicAdd(&lds[c.y - lo], wv.y);
        if (c.z >= lo && c.z < hi) atomicAdd(&lds[c.z - lo], wv.z);
        if (c.w >= lo && c.w < hi) atomicAdd(&lds[c.w - lo], wv.w);
    }
    if (g == G - 1) {  // scalar tail (E % 4), handled per-partition
        for (int t = e4 * 4 + threadIdx.x; t < e_total; t += blockDim.x) {
            int cc = col[t];
            if (cc >= lo && cc < hi) atomicAdd(&lds[cc - lo], w[t]);
        }
    }
    __syncthreads();

    // flush LDS partial -> private global slice, coalesced float4
    float* dst = partial + (size_t)(p * G + g) * PART;
    for (int i = threadIdx.x * 4; i < PART; i += blockDim.x * 4) {
        float4 v = *reinterpret_cast<const float4*>(&lds[i]);
        *reinterpret_cast<float4*>(&dst[i]) = v;
    }
}

// dinv[n] = (sum_g partial[p][g][i]) -> 0-safe rsqrt
__global__ void reduce_rsqrt_kernel(const float* __restrict__ partial,
                                    float* __restrict__ dinv, int G)
{
    int n = blockIdx.x * blockDim.x + threadIdx.x;
    if (n >= NN) return;
    int p = n / PART;
    int i = n - p * PART;
    const float* base = partial + (size_t)p * G * PART + i;
    float s = 0.0f;
    #pragma unroll 8
    for (int g = 0; g < G; ++g) s += base[(size_t)g * PART];
    dinv[n] = (s == 0.0f) ? 0.0f : rsqrtf(s);
}

// ============ fallback path (small ws): original atomic pipeline ============

__global__ void zero_deg(float* __restrict__ deg, int n) {
    int i = blockIdx.x * blockDim.x + threadIdx.x;
    int stride = gridDim.x * blockDim.x;
    for (; i < n; i += stride) deg[i] = 0.0f;
}

__global__ void degree_kernel(const int* __restrict__ col,
                              const float* __restrict__ w,
                              float* __restrict__ deg,
                              int e4, int e_total) {
    int i = blockIdx.x * blockDim.x + threadIdx.x;
    int stride = gridDim.x * blockDim.x;
    for (int v = i; v < e4; v += stride) {
        int4   c  = reinterpret_cast<const int4*>(col)[v];
        float4 wv = reinterpret_cast<const float4*>(w)[v];
        atomicAdd(&deg[c.x], wv.x);
        atomicAdd(&deg[c.y], wv.y);
        atomicAdd(&deg[c.z], wv.z);
        atomicAdd(&deg[c.w], wv.w);
    }
    for (int t = e4 * 4 + i; t < e_total; t += stride)
        atomicAdd(&deg[col[t]], w[t]);
}

__global__ void rsqrt_kernel(float* __restrict__ deg, int n) {
    int i = blockIdx.x * blockDim.x + threadIdx.x;
    int stride = gridDim.x * blockDim.x;
    for (; i < n; i += stride) {
        float d = deg[i];
        deg[i] = (d == 0.0f) ? 0.0f : rsqrtf(d);
    }
}

// ============ shared epilogue: out[e] = dinv[row[e]] * dinv[col[e]] =========

__global__ void norm_kernel(const int* __restrict__ row,
                            const int* __restrict__ col,
                            const float* __restrict__ dinv,
                            float* __restrict__ out,
                            int e4, int e_total) {
    int i = blockIdx.x * blockDim.x + threadIdx.x;
    int stride = gridDim.x * blockDim.x;
    for (int v = i; v < e4; v += stride) {
        int4 r = reinterpret_cast<const int4*>(row)[v];
        int4 c = reinterpret_cast<const int4*>(col)[v];
        float4 o;
        o.x = dinv[r.x] * dinv[c.x];
        o.y = dinv[r.y] * dinv[c.y];
        o.z = dinv[r.z] * dinv[c.z];
        o.w = dinv[r.w] * dinv[c.w];
        reinterpret_cast<float4*>(out)[v] = o;
    }
    for (int t = e4 * 4 + i; t < e_total; t += stride)
        out[t] = dinv[row[t]] * dinv[col[t]];
}

// ============================== launch ======================================

extern "C" void kernel_launch(void* const* d_in, const int* in_sizes, int n_in,
                              void* d_out, int out_size, void* d_ws, size_t ws_size,
                              hipStream_t stream) {
    const int*   edge_index = (const int*)d_in[0];
    const float* edge_w     = (const float*)d_in[1];
    const int E  = in_sizes[1];
    const int* row = edge_index;
    const int* col = edge_index + E;

    float* out  = (float*)d_out;
    float* dinv = (float*)d_ws;                       // NN floats, 16B-aligned
    const size_t DINV_BYTES = (size_t)NN * 4;         // 400,000 (mult of 16)

    const int B  = 256;
    const int e4 = E / 4;

    // choose slice count G from available scratch
    int G = 0;
    if (ws_size > DINV_BYTES) {
        size_t avail = ws_size - DINV_BYTES;
        size_t gmax  = avail / ((size_t)NPASS * PART * 4);
        G = (int)(gmax < 256 ? gmax : 256);
        G &= ~7;                                      // multiple of 8
    }

    if (G >= 16) {
        float* partial = (float*)((char*)d_ws + DINV_BYTES);
        int fancy = 1;                                // G % 8 == 0 guaranteed
        histo_kernel<<<NPASS * G, 1024, 0, stream>>>(col, edge_w, partial,
                                                     G, e4, E, fancy);
        reduce_rsqrt_kernel<<<(NN + B - 1) / B, B, 0, stream>>>(partial, dinv, G);
    } else {
        // fallback: global-atomic pipeline
        int gz = (NN + B - 1) / B; if (gz > 2048) gz = 2048;
        zero_deg<<<gz, B, 0, stream>>>(dinv, NN);
        int gd = (e4 + B - 1) / B; if (gd > 2048) gd = 2048;
        degree_kernel<<<gd, B, 0, stream>>>(col, edge_w, dinv, e4, E);
        rsqrt_kernel<<<gz, B, 0, stream>>>(dinv, NN);
    }

    int gn = (e4 + B - 1) / B; if (gn > 2048) gn = 2048;
    norm_kernel<<<gn, B, 0, stream>>>(row, col, dinv, out, e4, E);
}

// Round 4
// 104.703 us; speedup vs baseline: 3.7430x; 1.2607x over previous
//
#include <hip/hip_runtime.h>

#define NN    100000
#define PART  25000      // nodes per partition; LDS = 100 KB/block
#define NPASS 4          // NPASS * PART == NN exactly
#define GDEF  64         // edge chunks -> grid = NPASS*GDEF = 256 = 1 block/CU

typedef float f32x4 __attribute__((ext_vector_type(4)));

// ============ main path: privatized LDS histogram, no global atomics ========

__global__ __launch_bounds__(1024) void histo_kernel(
    const int* __restrict__ col, const float* __restrict__ w,
    float* __restrict__ partial,   // [NPASS*G][PART]
    int G, int e4, int e_total)
{
    __shared__ float lds[PART];

    // Same-chunk pass-blocks land on the same XCD (bid%8 round-robin):
    // group of 32 blocks = 8 chunks x 4 passes.
    int b = blockIdx.x;
    int q = b >> 5;           // group of 32 blocks
    int r = b & 31;
    int x = r & 7;            // xcd slot == chunk-within-group
    int p = r >> 3;           // pass 0..3
    int g = q * 8 + x;        // chunk id (requires G % 8 == 0)

    const int lo = p * PART;
    const int hi = lo + PART;

    for (int i = threadIdx.x; i < PART; i += blockDim.x) lds[i] = 0.0f;
    __syncthreads();

    const int C  = (e4 + G - 1) / G;
    const int v0 = g * C;
    const int v1 = min(e4, v0 + C);
    for (int v = v0 + threadIdx.x; v < v1; v += blockDim.x) {
        int4   c  = reinterpret_cast<const int4*>(col)[v];
        float4 wv = reinterpret_cast<const float4*>(w)[v];
        if (c.x >= lo && c.x < hi) atomicAdd(&lds[c.x - lo], wv.x);
        if (c.y >= lo && c.y < hi) atomicAdd(&lds[c.y - lo], wv.y);
        if (c.z >= lo && c.z < hi) atomicAdd(&lds[c.z - lo], wv.z);
        if (c.w >= lo && c.w < hi) atomicAdd(&lds[c.w - lo], wv.w);
    }
    if (g == G - 1) {  // scalar tail (E % 4)
        for (int t = e4 * 4 + threadIdx.x; t < e_total; t += blockDim.x) {
            int cc = col[t];
            if (cc >= lo && cc < hi) atomicAdd(&lds[cc - lo], w[t]);
        }
    }
    __syncthreads();

    // flush LDS partial -> private global slice, coalesced float4
    float* dst = partial + (size_t)(p * G + g) * PART;
    for (int i = threadIdx.x * 4; i < PART; i += blockDim.x * 4) {
        f32x4 v = *reinterpret_cast<const f32x4*>(&lds[i]);
        *reinterpret_cast<f32x4*>(&dst[i]) = v;
    }
}

// dinv[n] = (sum_g partial[p][g][i]) -> 0-safe rsqrt
__global__ void reduce_rsqrt_kernel(const float* __restrict__ partial,
                                    float* __restrict__ dinv, int G)
{
    int n = blockIdx.x * blockDim.x + threadIdx.x;
    if (n >= NN) return;
    int p = n / PART;
    int i = n - p * PART;
    const float* base = partial + (size_t)p * G * PART + i;
    float s = 0.0f;
    #pragma unroll 8
    for (int g = 0; g < G; ++g) s += base[(size_t)g * PART];
    dinv[n] = (s == 0.0f) ? 0.0f : rsqrtf(s);
}

// ============ fallback path (small ws): global-atomic pipeline ==============

__global__ void zero_deg(float* __restrict__ deg, int n) {
    int i = blockIdx.x * blockDim.x + threadIdx.x;
    int stride = gridDim.x * blockDim.x;
    for (; i < n; i += stride) deg[i] = 0.0f;
}

__global__ void degree_kernel(const int* __restrict__ col,
                              const float* __restrict__ w,
                              float* __restrict__ deg,
                              int e4, int e_total) {
    int i = blockIdx.x * blockDim.x + threadIdx.x;
    int stride = gridDim.x * blockDim.x;
    for (int v = i; v < e4; v += stride) {
        int4   c  = reinterpret_cast<const int4*>(col)[v];
        float4 wv = reinterpret_cast<const float4*>(w)[v];
        atomicAdd(&deg[c.x], wv.x);
        atomicAdd(&deg[c.y], wv.y);
        atomicAdd(&deg[c.z], wv.z);
        atomicAdd(&deg[c.w], wv.w);
    }
    for (int t = e4 * 4 + i; t < e_total; t += stride)
        atomicAdd(&deg[col[t]], w[t]);
}

__global__ void rsqrt_kernel(float* __restrict__ deg, int n) {
    int i = blockIdx.x * blockDim.x + threadIdx.x;
    int stride = gridDim.x * blockDim.x;
    for (; i < n; i += stride) {
        float d = deg[i];
        deg[i] = (d == 0.0f) ? 0.0f : rsqrtf(d);
    }
}

// ============ shared epilogue: out[e] = dinv[row[e]] * dinv[col[e]] =========

__global__ void norm_kernel(const int* __restrict__ row,
                            const int* __restrict__ col,
                            const float* __restrict__ dinv,
                            float* __restrict__ out,
                            int e4, int e_total) {
    int i = blockIdx.x * blockDim.x + threadIdx.x;
    int stride = gridDim.x * blockDim.x;
    for (int v = i; v < e4; v += stride) {
        int4 r = reinterpret_cast<const int4*>(row)[v];
        int4 c = reinterpret_cast<const int4*>(col)[v];
        f32x4 o;
        o.x = dinv[r.x] * dinv[c.x];
        o.y = dinv[r.y] * dinv[c.y];
        o.z = dinv[r.z] * dinv[c.z];
        o.w = dinv[r.w] * dinv[c.w];
        __builtin_nontemporal_store(o, &reinterpret_cast<f32x4*>(out)[v]);
    }
    for (int t = e4 * 4 + i; t < e_total; t += stride)
        out[t] = dinv[row[t]] * dinv[col[t]];
}

// ============================== launch ======================================

extern "C" void kernel_launch(void* const* d_in, const int* in_sizes, int n_in,
                              void* d_out, int out_size, void* d_ws, size_t ws_size,
                              hipStream_t stream) {
    const int*   edge_index = (const int*)d_in[0];
    const float* edge_w     = (const float*)d_in[1];
    const int E  = in_sizes[1];
    const int* row = edge_index;
    const int* col = edge_index + E;

    float* out  = (float*)d_out;
    float* dinv = (float*)d_ws;                       // NN floats, 16B-aligned
    const size_t DINV_BYTES = (size_t)NN * 4;         // 400,000 (mult of 16)

    const int B  = 256;
    const int e4 = E / 4;

    // choose slice count G from available scratch (cap at GDEF=64)
    int G = 0;
    if (ws_size > DINV_BYTES) {
        size_t avail = ws_size - DINV_BYTES;
        size_t gmax  = avail / ((size_t)NPASS * PART * 4);
        G = (int)(gmax < GDEF ? gmax : GDEF);
        G &= ~7;                                      // multiple of 8
    }

    if (G >= 16) {
        float* partial = (float*)((char*)d_ws + DINV_BYTES);
        histo_kernel<<<NPASS * G, 1024, 0, stream>>>(col, edge_w, partial,
                                                     G, e4, E);
        reduce_rsqrt_kernel<<<(NN + B - 1) / B, B, 0, stream>>>(partial, dinv, G);
    } else {
        int gz = (NN + B - 1) / B; if (gz > 2048) gz = 2048;
        zero_deg<<<gz, B, 0, stream>>>(dinv, NN);
        int gd = (e4 + B - 1) / B; if (gd > 2048) gd = 2048;
        degree_kernel<<<gd, B, 0, stream>>>(col, edge_w, dinv, e4, E);
        rsqrt_kernel<<<gz, B, 0, stream>>>(dinv, NN);
    }

    int gn = (e4 + B - 1) / B; if (gn > 2048) gn = 2048;
    norm_kernel<<<gn, B, 0, stream>>>(row, col, dinv, out, e4, E);
}